// Round 11
// baseline (225.123 us; speedup 1.0000x reference)
//
#include <hip/hip_runtime.h>

// GaLiTe attention layer, MI355X/gfx950 — fp32 pipeline, f16x3-split MFMA proj
// (R19) + register-fused-gate scan12 (R29) + f16x3 MFMA out (R28). 3 kernels.
// Shapes: T=64 B=16 DIM=512 H=8 Dh=64 ETA=4 FD=256.
// d_out = fp32 [ output(64*16*512) | kv_last(16*8*256*64) | nm_last(16*8*256) ].
//
// R29: scan11 PROVED the stall diagnosis (FETCH 17.5->10.9 MB reading
// L2-resident proj outputs) but died on its per-step __syncthreads (71 us).
// scan12 gets the same L2 win with NO barrier: gating computed in-register
// per lane. Lane's 8 D = one e (di=8*(li&7), e=li>>3): raw loads are 2x
// float4 each from kb/gb/qb + p1/p2/p3 + float2 v/bb — same bytes as scan8's
// gating loads but from the hot 10.8 MB proj region. +~11 sigmoid + ~60 mul
// per step (trans pipe, issued inside the prefetch latency window); the
// ~28 us HBM-miss stall collapses toward L2 latency. gate_kernel deleted.
// HAZARD (from scan11): attn must NOT overwrite vb (scan reads v per-step,
// sibling splits skewed) -> attn goes to the dead gating region.
// Gating exprs/order = gate_kernel's exactly; recurrence/reduce = scan8's.
//
// Ledger: scan5 58 / scan6 101 / scan7 67 / scan8 54 / scan9 73 / scan10 65 /
// scan11 71. Carried: proj f16x3 MFMA (Markidis hi+lo, ~22 bits, fp32 acc;
// bf16's 2^-8 failed R2/R3); out f16x3 MFMA single kernel (R28).

#define T_N   64
#define B_N   16
#define DIM_N 512
#define H_N   8
#define DH_N  64

#define OUT_ELEMS   524288   // T*B*DIM
#define KV_ELEMS    2097152  // B*H*FD*Dh
#define PROJ_ELEMS  2719744  // 5*524288 + 3*32768

typedef _Float16 f16;
typedef f16   f16x8 __attribute__((ext_vector_type(8)));
typedef float f32x4 __attribute__((ext_vector_type(4)));

__device__ __forceinline__ float sigmoidf_(float x) {
    return 1.0f / (1.0f + __expf(-x));
}

// ---------------------------------------------------------------------------
// DPP half-wave (32-lane) sum reduction, VALU-pipe only (no LDS). Half sums
// valid in lanes 16-31 (lo half) and 48-63 (hi half). PROVEN in scan8.
// ---------------------------------------------------------------------------
template <int CTRL, int RM>
__device__ __forceinline__ float dpp_add_(float x) {
    int mv = __builtin_amdgcn_update_dpp(__float_as_int(x), __float_as_int(x),
                                         CTRL, RM, 0xF, false);
    return x + __int_as_float(mv);
}
__device__ __forceinline__ float half_reduce_dpp(float x) {
    x = dpp_add_<0xB1, 0xF>(x);   // quad_perm [1,0,3,2]  (xor 1)
    x = dpp_add_<0x4E, 0xF>(x);   // quad_perm [2,3,0,1]  (xor 2)
    x = dpp_add_<0x141, 0xF>(x);  // row_half_mirror      (xor 4 equiv)
    x = dpp_add_<0x140, 0xF>(x);  // row_mirror           (xor 8 equiv)
    x = dpp_add_<0x142, 0xA>(x);  // row_bcast15 -> rows 1,3 (xor 16 equiv)
    return x;
}

// ---------------------------------------------------------------------------
// f16x3 split helper (PROVEN in proj): fp32 -> (hi, lo) f16 pair, ~22 bits.
// ---------------------------------------------------------------------------
__device__ __forceinline__ void cvt_split_store(f16* __restrict__ dh,
                                                f16* __restrict__ dl,
                                                float4 v0, float4 v1) {
    float x[8] = {v0.x, v0.y, v0.z, v0.w, v1.x, v1.y, v1.z, v1.w};
    f16x8 h, lo;
    #pragma unroll
    for (int e = 0; e < 8; ++e) {
        f16 hh = (f16)x[e];
        h[e]  = hh;
        lo[e] = (f16)(x[e] - (float)hh);
    }
    *(f16x8*)dh = h;
    *(f16x8*)dl = lo;
}

// ---------------------------------------------------------------------------
// mfma64_core: 64x64 tile f16x3 MFMA GEMM body (PROVEN, R19/R28).
// C[m][n] = sum_k A[m][k]*W[n][k] (+ bias[n]).
// ---------------------------------------------------------------------------
__device__ __forceinline__ void mfma64_core(const float* __restrict__ A,
                                            const float* __restrict__ W,
                                            const float* __restrict__ bias,
                                            float* __restrict__ C, int N,
                                            int mb, int nb) {
    const int nbase = nb * 64;
    if (nbase >= N) return;
    const int mbase = mb * 64;

    __shared__ f16 AsH[2][64][40];
    __shared__ f16 AsL[2][64][40];
    __shared__ f16 BsH[2][64][40];
    __shared__ f16 BsL[2][64][40];

    const int tid = threadIdx.x;
    const int sr = tid >> 2;
    const int kq = (tid & 3) << 3;
    const bool wok = (nbase + sr) < N;
    const float* Ap = A + (size_t)(mbase + sr) * 512 + kq;
    const float* Wp = W + (size_t)(nbase + sr) * 512 + kq;

    const int l  = tid & 63;
    const int w  = tid >> 6;
    const int wr = (w >> 1) << 5;
    const int wc = (w & 1) << 5;
    const int lr = l & 15;
    const int lk = (l >> 4) << 3;

    f32x4 acc[2][2] = {};

    float4 xa0 = *(const float4*)(Ap);
    float4 xa1 = *(const float4*)(Ap + 4);
    float4 wb0 = wok ? *(const float4*)(Wp)     : make_float4(0.f, 0.f, 0.f, 0.f);
    float4 wb1 = wok ? *(const float4*)(Wp + 4) : make_float4(0.f, 0.f, 0.f, 0.f);
    cvt_split_store(&AsH[0][sr][kq], &AsL[0][sr][kq], xa0, xa1);
    cvt_split_store(&BsH[0][sr][kq], &BsL[0][sr][kq], wb0, wb1);

    for (int k0 = 0; k0 < 512; k0 += 32) {
        const int buf = (k0 >> 5) & 1;
        __syncthreads();
        const bool more = (k0 + 32) < 512;
        if (more) {
            xa0 = *(const float4*)(Ap + k0 + 32);
            xa1 = *(const float4*)(Ap + k0 + 36);
            wb0 = wok ? *(const float4*)(Wp + k0 + 32) : make_float4(0.f, 0.f, 0.f, 0.f);
            wb1 = wok ? *(const float4*)(Wp + k0 + 36) : make_float4(0.f, 0.f, 0.f, 0.f);
        }

        f16x8 aH[2], aL[2], bH[2], bL[2];
        #pragma unroll
        for (int i = 0; i < 2; ++i) {
            const int row = wr + i * 16 + lr;
            aH[i] = *(const f16x8*)&AsH[buf][row][lk];
            aL[i] = *(const f16x8*)&AsL[buf][row][lk];
        }
        #pragma unroll
        for (int j = 0; j < 2; ++j) {
            const int col = wc + j * 16 + lr;
            bH[j] = *(const f16x8*)&BsH[buf][col][lk];
            bL[j] = *(const f16x8*)&BsL[buf][col][lk];
        }

        #pragma unroll
        for (int i = 0; i < 2; ++i)
            #pragma unroll
            for (int j = 0; j < 2; ++j) {
                acc[i][j] = __builtin_amdgcn_mfma_f32_16x16x32_f16(aH[i], bH[j], acc[i][j], 0, 0, 0);
                acc[i][j] = __builtin_amdgcn_mfma_f32_16x16x32_f16(aH[i], bL[j], acc[i][j], 0, 0, 0);
                acc[i][j] = __builtin_amdgcn_mfma_f32_16x16x32_f16(aL[i], bH[j], acc[i][j], 0, 0, 0);
            }

        if (more) {
            const int nbuf = buf ^ 1;
            cvt_split_store(&AsH[nbuf][sr][kq], &AsL[nbuf][sr][kq], xa0, xa1);
            cvt_split_store(&BsH[nbuf][sr][kq], &BsL[nbuf][sr][kq], wb0, wb1);
        }
    }

    // C/D layout (m89/m91): col = lane&15, row = (lane>>4)*4 + reg
    #pragma unroll
    for (int j = 0; j < 2; ++j) {
        const int n = nbase + wc + j * 16 + lr;
        if (n < N) {
            const float bv = bias ? bias[n] : 0.f;
            #pragma unroll
            for (int i = 0; i < 2; ++i) {
                #pragma unroll
                for (int q = 0; q < 4; ++q) {
                    const int m = mbase + wr + i * 16 + ((l >> 4) << 2) + q;
                    C[(size_t)m * N + n] = acc[i][j][q] + bv;
                }
            }
        }
    }
}

struct ProjW {
    const float* W[8];
    float*       D[8];
};

// proj (R19, PROVEN): grid 1024, id = z + 8*(m + 16*n); XCD = z.
__global__ __launch_bounds__(256) void proj_mfma_kernel(const float* __restrict__ X,
                                                        ProjW a) {
    const int id = blockIdx.x;
    const int z = id & 7;
    const int rem = id >> 3;
    const int mb = rem & 15;
    const int nb = rem >> 4;
    const int N = (z < 5) ? 512 : 32;
    mfma64_core(X, a.W[z], nullptr, a.D[z], N, mb, nb);
}

// out (R28): one f16x3 MFMA GEMM, grid 128 = 16 mb x 8 nb.
__global__ __launch_bounds__(256) void out_mfma_kernel(const float* __restrict__ A,
                                                       const float* __restrict__ W,
                                                       const float* __restrict__ bias,
                                                       float* __restrict__ C) {
    const int id = blockIdx.x;
    const int mb = id & 15;
    const int nb = id >> 4;
    mfma64_core(A, W, bias, C, 512, mb, nb);
}

// ---------------------------------------------------------------------------
// scan12 (R29): scan8 structure + gating computed IN-REGISTER per lane (no
// LDS, no barrier). Grid 512: blk = s*128 + bh (XCD = bh%8 = h). Block 256 =
// 4 waves; wave = 2 INDEPENDENT 32-lane halves. Half (l>>5) owns cols
// s*16+w*4+2*half+{0,1}. Lane li = l&31 owns D = 8*li..8*li+7, which is a
// single e = li>>3, di = 8*(li&7)..+7. Per step: raw loads for t+1 issued
// early (kb/gb/qb 2xfloat4 each, p1/p2/p3, term, v/bb float2 — all from the
// L2-resident proj region); gating for t computed from current raw regs with
// gate_kernel's exact expressions; recurrence + DPP reduce = scan8 verbatim.
// attn written to a SEPARATE dead buffer (NOT vb — scan reads v per-step).
// ---------------------------------------------------------------------------
__global__ __launch_bounds__(256) void scan12_kernel(
    const float* __restrict__ qb, const float* __restrict__ kb,
    const float* __restrict__ vbi, const float* __restrict__ bb,
    const float* __restrict__ gb, const float* __restrict__ p1b,
    const float* __restrict__ p2b, const float* __restrict__ p3b,
    const int* __restrict__ term,
    float* __restrict__ attn,
    const float* __restrict__ kv0, const float* __restrict__ nm0,
    float* __restrict__ dout) {
    const int blk = blockIdx.x;       // 512 = 4 splits x 128 bh
    const int bh = blk & 127;
    const int s  = blk >> 7;          // 0..3
    const int b  = bh >> 3;
    const int h  = bh & 7;
    const int tid = threadIdx.x;
    const int w = tid >> 6;
    const int l = tid & 63;
    const int half = l >> 5;
    const int li = l & 31;
    const int d0 = s * 16 + w * 4 + half * 2;   // lane's 2 d-cols
    const int D0 = li << 3;                     // lane's 8 D
    const int di0 = (D0 & 63);                  // 8*(li&7)
    const int e   = D0 >> 6;                    // li>>3

    float kv[8][2];
    float nm[8];
    {
        const float* kp = kv0 + ((size_t)bh * 256 + D0) * 64 + d0;
        #pragma unroll
        for (int j = 0; j < 8; ++j) {
            float2 r = *(const float2*)(kp + (size_t)j * 64);
            kv[j][0] = r.x; kv[j][1] = r.y;
        }
        float4 na  = *(const float4*)(nm0 + (size_t)bh * 256 + D0);
        float4 nb_ = *(const float4*)(nm0 + (size_t)bh * 256 + D0 + 4);
        nm[0] = na.x; nm[1] = na.y; nm[2] = na.z; nm[3] = na.w;
        nm[4] = nb_.x; nm[5] = nb_.y; nm[6] = nb_.z; nm[7] = nb_.w;
    }

    // raw-input register buffers (current step)
    float4 ck0, ck1, cg0, cg1, cq0, cq1;  // k, g, q (8 each)
    float  cp1, cp2, cp3, cmask;
    float2 cvv, cbb;

    {
        const size_t base = (size_t)b * 512 + h * 64;
        const size_t pb = (size_t)b * 32 + h * 4 + e;
        ck0 = *(const float4*)(kb + base + di0); ck1 = *(const float4*)(kb + base + di0 + 4);
        cg0 = *(const float4*)(gb + base + di0); cg1 = *(const float4*)(gb + base + di0 + 4);
        cq0 = *(const float4*)(qb + base + di0); cq1 = *(const float4*)(qb + base + di0 + 4);
        cp1 = p1b[pb]; cp2 = p2b[pb]; cp3 = p3b[pb];
        cmask = 1.0f - (float)term[b];
        cvv = *(const float2*)(vbi + base + d0);
        cbb = *(const float2*)(bb + base + d0);
    }

    for (int t = 0; t < T_N; ++t) {
        const int row = t * B_N + b;

        // issue raw loads for t+1 early (L2-resident proj outputs)
        float4 nk0 = {}, nk1 = {}, ng0 = {}, ng1 = {}, nq0 = {}, nq1 = {};
        float  np1 = 0.f, np2 = 0.f, np3 = 0.f, nmask = 0.f;
        float2 nvv = {}, nbb = {};
        if (t + 1 < T_N) {
            const size_t nbase = (size_t)(row + B_N) * 512 + h * 64;
            const size_t npb = (size_t)(row + B_N) * 32 + h * 4 + e;
            nk0 = *(const float4*)(kb + nbase + di0); nk1 = *(const float4*)(kb + nbase + di0 + 4);
            ng0 = *(const float4*)(gb + nbase + di0); ng1 = *(const float4*)(gb + nbase + di0 + 4);
            nq0 = *(const float4*)(qb + nbase + di0); nq1 = *(const float4*)(qb + nbase + di0 + 4);
            np1 = p1b[npb]; np2 = p2b[npb]; np3 = p3b[npb];
            nmask = 1.0f - (float)term[row + B_N];
            nvv = *(const float2*)(vbi + nbase + d0);
            nbb = *(const float2*)(bb + nbase + d0);
        }

        // gating for t from current raw regs (gate_kernel's exact exprs)
        const float kj[8] = {ck0.x, ck0.y, ck0.z, ck0.w, ck1.x, ck1.y, ck1.z, ck1.w};
        const float gj[8] = {cg0.x, cg0.y, cg0.z, cg0.w, cg1.x, cg1.y, cg1.z, cg1.w};
        const float qj[8] = {cq0.x, cq0.y, cq0.z, cq0.w, cq1.x, cq1.y, cq1.z, cq1.w};
        const float sp3 = sigmoidf_(cp3);
        const float r1 = fmaxf(cp1, 0.f);
        const float r2 = fmaxf(cp2, 0.f);
        float dj[8], gkj[8], phj[8];
        #pragma unroll
        for (int j = 0; j < 8; ++j) {
            const float gf = sp3 * sigmoidf_(gj[j]);
            dj[j]  = (1.0f - gf) * cmask;
            gkj[j] = r1 * kj[j] * gf;
            phj[j] = r2 * qj[j];
        }
        const float gvx = cvv.x * sigmoidf_(cbb.x);
        const float gvy = cvv.y * sigmoidf_(cbb.y);

        // recurrence + reduce (scan8 verbatim)
        float den = 0.f, n0 = 0.f, n1 = 0.f;
        #pragma unroll
        for (int j = 0; j < 8; ++j) {
            nm[j] = dj[j] * nm[j] + gkj[j];
            den = fmaf(phj[j], nm[j], den);
            kv[j][0] = dj[j] * kv[j][0] + gkj[j] * gvx; n0 = fmaf(phj[j], kv[j][0], n0);
            kv[j][1] = dj[j] * kv[j][1] + gkj[j] * gvy; n1 = fmaf(phj[j], kv[j][1], n1);
        }

        n0  = half_reduce_dpp(n0);
        n1  = half_reduce_dpp(n1);
        den = half_reduce_dpp(den);

        if (li == 16) {
            const size_t obase = (size_t)row * 512 + h * 64;
            attn[obase + d0]     = n0 / (den + 1e-6f);
            attn[obase + d0 + 1] = n1 / (den + 1e-6f);
        }

        ck0 = nk0; ck1 = nk1; cg0 = ng0; cg1 = ng1; cq0 = nq0; cq1 = nq1;
        cp1 = np1; cp2 = np2; cp3 = np3; cmask = nmask; cvv = nvv; cbb = nbb;
    }

    {
        float* kp = dout + OUT_ELEMS + ((size_t)bh * 256 + D0) * 64 + d0;
        #pragma unroll
        for (int j = 0; j < 8; ++j)
            *(float2*)(kp + (size_t)j * 64) = make_float2(kv[j][0], kv[j][1]);
        if (s == 0 && w == 0 && half == 0) {
            float* np = dout + OUT_ELEMS + KV_ELEMS + (size_t)bh * 256 + D0;
            *(float4*)np       = make_float4(nm[0], nm[1], nm[2], nm[3]);
            *(float4*)(np + 4) = make_float4(nm[4], nm[5], nm[6], nm[7]);
        }
    }
}

// ---------------------------------------------------------------------------
extern "C" void kernel_launch(void* const* d_in, const int* in_sizes, int n_in,
                              void* d_out, int out_size, void* d_ws, size_t ws_size,
                              hipStream_t stream) {
    (void)in_sizes; (void)n_in; (void)out_size; (void)ws_size;

    const float* X    = (const float*)d_in[0];
    const int*   term = (const int*)  d_in[1];
    const float* kv0  = (const float*)d_in[2];
    const float* nm0  = (const float*)d_in[3];
    const float* Wo   = (const float*)d_in[12];
    const float* bo   = (const float*)d_in[13];

    float* out = (float*)d_out;

    // ---- workspace (layout kept; gating region now hosts attn only) ----
    float* qb  = (float*)d_ws;            // proj outputs (read by scan12)
    float* kb  = qb  + 524288;
    float* vb  = kb  + 524288;            // v — pristine through scan12
    float* bb  = vb  + 524288;
    float* gb  = bb  + 524288;
    float* p1b = gb  + 524288;
    float* p2b = p1b + 32768;
    float* p3b = p2b + 32768;
    float* attn = p3b + 32768;            // attn output (ex-gating region)

    ProjW pa;
    pa.W[0] = (const float*)d_in[4];  pa.W[1] = (const float*)d_in[5];
    pa.W[2] = (const float*)d_in[6];  pa.W[3] = (const float*)d_in[7];
    pa.W[4] = (const float*)d_in[8];  pa.W[5] = (const float*)d_in[9];
    pa.W[6] = (const float*)d_in[10]; pa.W[7] = (const float*)d_in[11];
    pa.D[0] = qb;  pa.D[1] = kb;  pa.D[2] = vb;  pa.D[3] = bb;
    pa.D[4] = gb;  pa.D[5] = p1b; pa.D[6] = p2b; pa.D[7] = p3b;
    proj_mfma_kernel<<<1024, 256, 0, stream>>>(X, pa);

    scan12_kernel<<<512, 256, 0, stream>>>(qb, kb, vb, bb, gb,
                                           p1b, p2b, p3b, term,
                                           attn, kv0, nm0, out);

    // out = attn @ Wo^T + bo — single f16x3 MFMA GEMM (R28)
    out_mfma_kernel<<<128, 256, 0, stream>>>(attn, Wo, bo, out);
}

// Round 15
// 186.443 us; speedup vs baseline: 1.2075x; 1.2075x over previous
//
#include <hip/hip_runtime.h>

// GaLiTe attention layer, MI355X/gfx950 — fp32 pipeline, f16x3-split MFMA proj
// (R19) + scan8 (best scan) + f16x3 MFMA out (R28) + NON-TEMPORAL dead-write
// stores (R30; compile-fixed R31; resubmitted R33 — R31/R32 benches were
// broker GPUAcquisitionTimeouts, kernel never ran). 4 kernels.
// Shapes: T=64 B=16 DIM=512 H=8 Dh=64 ETA=4 FD=256.
// d_out = fp32 [ output(64*16*512) | kv_last(16*8*256*64) | nm_last(16*8*256) ].
//
// R30 theory: scan8's kv/nm epilogue (8 MB to d_out, never re-read on device)
// and out_mfma's final C (2 MB) evict gating lines from L2 that late blocks
// still need (gating = 3.25 MB/XCD vs 4 MB L2; FETCH 17.5 of 26 MB says ~2/3
// miss). NT stores bypass L2 allocation; values bit-identical.
//
// Scan ledger (CLOSED): scan5 58 / scan6 101 / scan7 67 / scan8 54 / scan9 73
// / scan10 65 / scan11 71 / scan12 112. scan8 is structurally latency-bound
// at 2 blocks/CU; every restructuring traded the stall for a bigger cost.
//
// Carried:
//  - proj mfma_f32_16x16x32_f16 Markidis hi+lo split (3 MFMA/frag): ~22
//    mantissa bits, rel err ~1e-6 (bf16's 2^-8 failed in R2/R3). acc fp32.
//  - gate precompute: ~10 us (transcendentals off the scan chain, amortized).
//  - scan8: 4 d-splits, 32-lane halves, DPP reduce (VALU pipe), depth-1
//    rotation, li==16 writer. attn overwrites vb (scan never reads vb).
//  - out: single f16x3 MFMA GEMM, grid 128 (R28).

#define T_N   64
#define B_N   16
#define DIM_N 512
#define H_N   8
#define DH_N  64

#define OUT_ELEMS   524288   // T*B*DIM
#define KV_ELEMS    2097152  // B*H*FD*Dh
#define PROJ_ELEMS  2719744  // 5*524288 + 3*32768

typedef _Float16 f16;
typedef f16   f16x8 __attribute__((ext_vector_type(8)));
typedef float f32x4 __attribute__((ext_vector_type(4)));
typedef float f32x2 __attribute__((ext_vector_type(2)));

__device__ __forceinline__ float sigmoidf_(float x) {
    return 1.0f / (1.0f + __expf(-x));
}

// NT store helpers: builtin accepts clang native vectors only.
__device__ __forceinline__ void nt_store2(float* p, float a, float b) {
    f32x2 v; v.x = a; v.y = b;
    __builtin_nontemporal_store(v, (f32x2*)p);
}
__device__ __forceinline__ void nt_store4(float* p, float a, float b, float c, float d) {
    f32x4 v; v.x = a; v.y = b; v.z = c; v.w = d;
    __builtin_nontemporal_store(v, (f32x4*)p);
}

// ---------------------------------------------------------------------------
// DPP half-wave (32-lane) sum reduction, VALU-pipe only (no LDS). Half sums
// valid in lanes 16-31 (lo half) and 48-63 (hi half). PROVEN in scan8.
// ---------------------------------------------------------------------------
template <int CTRL, int RM>
__device__ __forceinline__ float dpp_add_(float x) {
    int mv = __builtin_amdgcn_update_dpp(__float_as_int(x), __float_as_int(x),
                                         CTRL, RM, 0xF, false);
    return x + __int_as_float(mv);
}
__device__ __forceinline__ float half_reduce_dpp(float x) {
    x = dpp_add_<0xB1, 0xF>(x);   // quad_perm [1,0,3,2]  (xor 1)
    x = dpp_add_<0x4E, 0xF>(x);   // quad_perm [2,3,0,1]  (xor 2)
    x = dpp_add_<0x141, 0xF>(x);  // row_half_mirror      (xor 4 equiv)
    x = dpp_add_<0x140, 0xF>(x);  // row_mirror           (xor 8 equiv)
    x = dpp_add_<0x142, 0xA>(x);  // row_bcast15 -> rows 1,3 (xor 16 equiv)
    return x;
}

// ---------------------------------------------------------------------------
// f16x3 split helper (PROVEN in proj): fp32 -> (hi, lo) f16 pair, ~22 bits.
// ---------------------------------------------------------------------------
__device__ __forceinline__ void cvt_split_store(f16* __restrict__ dh,
                                                f16* __restrict__ dl,
                                                float4 v0, float4 v1) {
    float x[8] = {v0.x, v0.y, v0.z, v0.w, v1.x, v1.y, v1.z, v1.w};
    f16x8 h, lo;
    #pragma unroll
    for (int e = 0; e < 8; ++e) {
        f16 hh = (f16)x[e];
        h[e]  = hh;
        lo[e] = (f16)(x[e] - (float)hh);
    }
    *(f16x8*)dh = h;
    *(f16x8*)dl = lo;
}

// ---------------------------------------------------------------------------
// mfma64_core: 64x64 tile f16x3 MFMA GEMM body (PROVEN, R19/R28).
// C[m][n] = sum_k A[m][k]*W[n][k] (+ bias[n]). NT = non-temporal C stores.
// ---------------------------------------------------------------------------
template <bool NT>
__device__ __forceinline__ void mfma64_core(const float* __restrict__ A,
                                            const float* __restrict__ W,
                                            const float* __restrict__ bias,
                                            float* __restrict__ C, int N,
                                            int mb, int nb) {
    const int nbase = nb * 64;
    if (nbase >= N) return;
    const int mbase = mb * 64;

    __shared__ f16 AsH[2][64][40];
    __shared__ f16 AsL[2][64][40];
    __shared__ f16 BsH[2][64][40];
    __shared__ f16 BsL[2][64][40];

    const int tid = threadIdx.x;
    const int sr = tid >> 2;
    const int kq = (tid & 3) << 3;
    const bool wok = (nbase + sr) < N;
    const float* Ap = A + (size_t)(mbase + sr) * 512 + kq;
    const float* Wp = W + (size_t)(nbase + sr) * 512 + kq;

    const int l  = tid & 63;
    const int w  = tid >> 6;
    const int wr = (w >> 1) << 5;
    const int wc = (w & 1) << 5;
    const int lr = l & 15;
    const int lk = (l >> 4) << 3;

    f32x4 acc[2][2] = {};

    float4 xa0 = *(const float4*)(Ap);
    float4 xa1 = *(const float4*)(Ap + 4);
    float4 wb0 = wok ? *(const float4*)(Wp)     : make_float4(0.f, 0.f, 0.f, 0.f);
    float4 wb1 = wok ? *(const float4*)(Wp + 4) : make_float4(0.f, 0.f, 0.f, 0.f);
    cvt_split_store(&AsH[0][sr][kq], &AsL[0][sr][kq], xa0, xa1);
    cvt_split_store(&BsH[0][sr][kq], &BsL[0][sr][kq], wb0, wb1);

    for (int k0 = 0; k0 < 512; k0 += 32) {
        const int buf = (k0 >> 5) & 1;
        __syncthreads();
        const bool more = (k0 + 32) < 512;
        if (more) {
            xa0 = *(const float4*)(Ap + k0 + 32);
            xa1 = *(const float4*)(Ap + k0 + 36);
            wb0 = wok ? *(const float4*)(Wp + k0 + 32) : make_float4(0.f, 0.f, 0.f, 0.f);
            wb1 = wok ? *(const float4*)(Wp + k0 + 36) : make_float4(0.f, 0.f, 0.f, 0.f);
        }

        f16x8 aH[2], aL[2], bH[2], bL[2];
        #pragma unroll
        for (int i = 0; i < 2; ++i) {
            const int row = wr + i * 16 + lr;
            aH[i] = *(const f16x8*)&AsH[buf][row][lk];
            aL[i] = *(const f16x8*)&AsL[buf][row][lk];
        }
        #pragma unroll
        for (int j = 0; j < 2; ++j) {
            const int col = wc + j * 16 + lr;
            bH[j] = *(const f16x8*)&BsH[buf][col][lk];
            bL[j] = *(const f16x8*)&BsL[buf][col][lk];
        }

        #pragma unroll
        for (int i = 0; i < 2; ++i)
            #pragma unroll
            for (int j = 0; j < 2; ++j) {
                acc[i][j] = __builtin_amdgcn_mfma_f32_16x16x32_f16(aH[i], bH[j], acc[i][j], 0, 0, 0);
                acc[i][j] = __builtin_amdgcn_mfma_f32_16x16x32_f16(aH[i], bL[j], acc[i][j], 0, 0, 0);
                acc[i][j] = __builtin_amdgcn_mfma_f32_16x16x32_f16(aL[i], bH[j], acc[i][j], 0, 0, 0);
            }

        if (more) {
            const int nbuf = buf ^ 1;
            cvt_split_store(&AsH[nbuf][sr][kq], &AsL[nbuf][sr][kq], xa0, xa1);
            cvt_split_store(&BsH[nbuf][sr][kq], &BsL[nbuf][sr][kq], wb0, wb1);
        }
    }

    // C/D layout (m89/m91): col = lane&15, row = (lane>>4)*4 + reg
    #pragma unroll
    for (int j = 0; j < 2; ++j) {
        const int n = nbase + wc + j * 16 + lr;
        if (n < N) {
            const float bv = bias ? bias[n] : 0.f;
            #pragma unroll
            for (int i = 0; i < 2; ++i) {
                #pragma unroll
                for (int q = 0; q < 4; ++q) {
                    const int m = mbase + wr + i * 16 + ((l >> 4) << 2) + q;
                    float v = acc[i][j][q] + bv;
                    if (NT) __builtin_nontemporal_store(v, &C[(size_t)m * N + n]);
                    else    C[(size_t)m * N + n] = v;
                }
            }
        }
    }
}

struct ProjW {
    const float* W[8];
    float*       D[8];
};

// proj (R19, PROVEN): grid 1024, id = z + 8*(m + 16*n); XCD = z.
// Outputs ARE re-read (gate/scan) -> cached stores.
__global__ __launch_bounds__(256) void proj_mfma_kernel(const float* __restrict__ X,
                                                        ProjW a) {
    const int id = blockIdx.x;
    const int z = id & 7;
    const int rem = id >> 3;
    const int mb = rem & 15;
    const int nb = rem >> 4;
    const int N = (z < 5) ? 512 : 32;
    mfma64_core<false>(X, a.W[z], nullptr, a.D[z], N, mb, nb);
}

// out (R28): one f16x3 MFMA GEMM, grid 128 = 16 mb x 8 nb. Final output —
// never re-read on device -> NON-TEMPORAL stores (R30).
__global__ __launch_bounds__(256) void out_mfma_kernel(const float* __restrict__ A,
                                                       const float* __restrict__ W,
                                                       const float* __restrict__ bias,
                                                       float* __restrict__ C) {
    const int id = blockIdx.x;
    const int mb = id & 15;
    const int nb = id >> 4;
    mfma64_core<true>(A, W, bias, C, 512, mb, nb);
}

// ---------------------------------------------------------------------------
// gate_kernel (R22, PROVEN): precompute disc/gk/phiq per (t,b,h,D), gv per
// (t,b,h,d). grid (8 h, 1024 rows) -> wg id % 8 = h (writer XCD = scan XCD).
// Gating outputs ARE the scan's hot data -> cached stores.
// ---------------------------------------------------------------------------
__global__ __launch_bounds__(256) void gate_kernel(
    const float* __restrict__ qb,  const float* __restrict__ kb,
    const float* __restrict__ vb,  const float* __restrict__ bb,
    const float* __restrict__ gb,  const float* __restrict__ p1b,
    const float* __restrict__ p2b, const float* __restrict__ p3b,
    const int* __restrict__ term,
    float* __restrict__ disc_g, float* __restrict__ gk_g,
    float* __restrict__ phiq_g, float* __restrict__ gv_g) {
    const int h = blockIdx.x;
    const int row = blockIdx.y;        // t*16 + b
    const int D = threadIdx.x;
    const int e = D >> 6, di = D & 63;
    const size_t base = (size_t)row * 512 + h * 64;
    const size_t pb = (size_t)row * 32 + h * 4;

    float q = qb[base + di], k = kb[base + di], g = gb[base + di];
    float p1 = p1b[pb + e], p2 = p2b[pb + e], p3 = p3b[pb + e];
    float mask = 1.0f - (float)term[row];
    float gf = sigmoidf_(p3) * sigmoidf_(g);

    const size_t o = ((size_t)row * 8 + h) * 256 + D;
    disc_g[o] = (1.0f - gf) * mask;
    gk_g[o]   = fmaxf(p1, 0.f) * k * gf;
    phiq_g[o] = fmaxf(p2, 0.f) * q;
    if (D < 64)
        gv_g[((size_t)row * 8 + h) * 64 + D] = vb[base + D] * sigmoidf_(bb[base + D]);
}

// ---------------------------------------------------------------------------
// scan8 (R22, PROVEN best): 4 d-splits. Grid 512: blk = s*128 + bh (XCD =
// bh%8 = h). Block 256 thr = 4 waves; wave = 2 INDEPENDENT 32-lane halves.
// Half (l>>5) owns cols s*16+w*4+2*half+{0,1}. Lane li = l&31 owns
// D = 8*li..8*li+8. Depth-1 load rotation; DPP reduce on VALU pipe; sums
// valid at li==16. attn overwrites vb (scan never reads vb).
// R30: kv/nm epilogue stores to d_out are NON-TEMPORAL (never re-read on
// device; stop early finishers evicting gating lines late blocks need).
// ---------------------------------------------------------------------------
__global__ __launch_bounds__(256) void scan8_kernel(
    const float* __restrict__ disc_g, const float* __restrict__ gk_g,
    const float* __restrict__ phiq_g, const float* __restrict__ gv_g,
    float* __restrict__ vb /* attn out */,
    const float* __restrict__ kv0, const float* __restrict__ nm0,
    float* __restrict__ dout) {
    const int blk = blockIdx.x;       // 512 = 4 splits x 128 bh
    const int bh = blk & 127;
    const int s  = blk >> 7;          // 0..3
    const int b  = bh >> 3;
    const int h  = bh & 7;
    const int tid = threadIdx.x;
    const int w = tid >> 6;
    const int l = tid & 63;
    const int half = l >> 5;
    const int li = l & 31;
    const int d0 = s * 16 + w * 4 + half * 2;   // lane's 2 d-cols
    const int D0 = li << 3;                     // lane's 8 D

    float kv[8][2];
    float nm[8];
    {
        const float* kp = kv0 + ((size_t)bh * 256 + D0) * 64 + d0;
        #pragma unroll
        for (int j = 0; j < 8; ++j) {
            float2 r = *(const float2*)(kp + (size_t)j * 64);
            kv[j][0] = r.x; kv[j][1] = r.y;
        }
        float4 na  = *(const float4*)(nm0 + (size_t)bh * 256 + D0);
        float4 nb_ = *(const float4*)(nm0 + (size_t)bh * 256 + D0 + 4);
        nm[0] = na.x; nm[1] = na.y; nm[2] = na.z; nm[3] = na.w;
        nm[4] = nb_.x; nm[5] = nb_.y; nm[6] = nb_.z; nm[7] = nb_.w;
    }

    float4 cd0, cd1, cg0, cg1, cp0, cp1; float2 cgv;
    {
        const size_t go = ((size_t)b * 8 + h) * 256 + D0;
        cd0 = *(const float4*)(disc_g + go);  cd1 = *(const float4*)(disc_g + go + 4);
        cg0 = *(const float4*)(gk_g + go);    cg1 = *(const float4*)(gk_g + go + 4);
        cp0 = *(const float4*)(phiq_g + go);  cp1 = *(const float4*)(phiq_g + go + 4);
        cgv = *(const float2*)(gv_g + ((size_t)b * 8 + h) * 64 + d0);
    }

    for (int t = 0; t < T_N; ++t) {
        const int row = t * B_N + b;
        const size_t base = (size_t)row * 512 + h * 64;

        float4 nd0 = {}, nd1 = {}, ng0 = {}, ng1 = {}, np0 = {}, np1 = {};
        float2 ngv = {};
        if (t + 1 < T_N) {
            const size_t go2 = ((size_t)(row + B_N) * 8 + h) * 256 + D0;
            nd0 = *(const float4*)(disc_g + go2); nd1 = *(const float4*)(disc_g + go2 + 4);
            ng0 = *(const float4*)(gk_g + go2);   ng1 = *(const float4*)(gk_g + go2 + 4);
            np0 = *(const float4*)(phiq_g + go2); np1 = *(const float4*)(phiq_g + go2 + 4);
            ngv = *(const float2*)(gv_g + ((size_t)(row + B_N) * 8 + h) * 64 + d0);
        }

        const float dj[8]  = {cd0.x, cd0.y, cd0.z, cd0.w, cd1.x, cd1.y, cd1.z, cd1.w};
        const float gkj[8] = {cg0.x, cg0.y, cg0.z, cg0.w, cg1.x, cg1.y, cg1.z, cg1.w};
        const float phj[8] = {cp0.x, cp0.y, cp0.z, cp0.w, cp1.x, cp1.y, cp1.z, cp1.w};

        float den = 0.f, n0 = 0.f, n1 = 0.f;
        #pragma unroll
        for (int j = 0; j < 8; ++j) {
            nm[j] = dj[j] * nm[j] + gkj[j];
            den = fmaf(phj[j], nm[j], den);
            kv[j][0] = dj[j] * kv[j][0] + gkj[j] * cgv.x; n0 = fmaf(phj[j], kv[j][0], n0);
            kv[j][1] = dj[j] * kv[j][1] + gkj[j] * cgv.y; n1 = fmaf(phj[j], kv[j][1], n1);
        }

        n0  = half_reduce_dpp(n0);
        n1  = half_reduce_dpp(n1);
        den = half_reduce_dpp(den);

        if (li == 16) {
            vb[base + d0]     = n0 / (den + 1e-6f);
            vb[base + d0 + 1] = n1 / (den + 1e-6f);
        }

        cd0 = nd0; cd1 = nd1; cg0 = ng0; cg1 = ng1; cp0 = np0; cp1 = np1; cgv = ngv;
    }

    {
        float* kp = dout + OUT_ELEMS + ((size_t)bh * 256 + D0) * 64 + d0;
        #pragma unroll
        for (int j = 0; j < 8; ++j)
            nt_store2(kp + (size_t)j * 64, kv[j][0], kv[j][1]);
        if (s == 0 && w == 0 && half == 0) {
            float* np = dout + OUT_ELEMS + KV_ELEMS + (size_t)bh * 256 + D0;
            nt_store4(np,     nm[0], nm[1], nm[2], nm[3]);
            nt_store4(np + 4, nm[4], nm[5], nm[6], nm[7]);
        }
    }
}

// ---------------------------------------------------------------------------
extern "C" void kernel_launch(void* const* d_in, const int* in_sizes, int n_in,
                              void* d_out, int out_size, void* d_ws, size_t ws_size,
                              hipStream_t stream) {
    (void)in_sizes; (void)n_in; (void)out_size; (void)ws_size;

    const float* X    = (const float*)d_in[0];
    const int*   term = (const int*)  d_in[1];
    const float* kv0  = (const float*)d_in[2];
    const float* nm0  = (const float*)d_in[3];
    const float* Wo   = (const float*)d_in[12];
    const float* bo   = (const float*)d_in[13];

    float* out = (float*)d_out;

    // ---- workspace (38.1 MB total — PROVEN available since R9) ----
    float* qb  = (float*)d_ws;            // proj outputs
    float* kb  = qb  + 524288;
    float* vb  = kb  + 524288;            // v, later attn
    float* bb  = vb  + 524288;
    float* gb  = bb  + 524288;
    float* p1b = gb  + 524288;
    float* p2b = p1b + 32768;
    float* p3b = p2b + 32768;
    float* disc_g = p3b + 32768;          // 26 MB gating region
    float* gk_g   = disc_g + 2097152;
    float* phiq_g = gk_g   + 2097152;
    float* gv_g   = phiq_g + 2097152;

    ProjW pa;
    pa.W[0] = (const float*)d_in[4];  pa.W[1] = (const float*)d_in[5];
    pa.W[2] = (const float*)d_in[6];  pa.W[3] = (const float*)d_in[7];
    pa.W[4] = (const float*)d_in[8];  pa.W[5] = (const float*)d_in[9];
    pa.W[6] = (const float*)d_in[10]; pa.W[7] = (const float*)d_in[11];
    pa.D[0] = qb;  pa.D[1] = kb;  pa.D[2] = vb;  pa.D[3] = bb;
    pa.D[4] = gb;  pa.D[5] = p1b; pa.D[6] = p2b; pa.D[7] = p3b;
    proj_mfma_kernel<<<1024, 256, 0, stream>>>(X, pa);

    gate_kernel<<<dim3(8, 1024), 256, 0, stream>>>(qb, kb, vb, bb, gb,
                                                   p1b, p2b, p3b, term,
                                                   disc_g, gk_g, phiq_g, gv_g);
    scan8_kernel<<<512, 256, 0, stream>>>(disc_g, gk_g, phiq_g, gv_g,
                                          vb, kv0, nm0, out);
    // out = attn @ Wo^T + bo — single f16x3 MFMA GEMM (R28), NT stores (R30)
    out_mfma_kernel<<<128, 256, 0, stream>>>(vb, Wo, bo, out);
}

// Round 17
// 182.117 us; speedup vs baseline: 1.2361x; 1.0238x over previous
//
#include <hip/hip_runtime.h>

// GaLiTe attention layer, MI355X/gfx950 — fp32 pipeline, f16x3-split MFMA proj
// (R19) + gf-compressed scan13 (R34; resubmitted R36 — R35 bench was a broker
// GPUAcquisitionTimeout, kernel never ran) + f16x3 MFMA out (R28). 4 kernels.
// Shapes: T=64 B=16 DIM=512 H=8 Dh=64 ETA=4 FD=256.
// d_out = fp32 [ output(64*16*512) | kv_last(16*8*256*64) | nm_last(16*8*256) ].
//
// R34: NT-store experiment (R30-33) REVERTED — FETCH unchanged (eviction
// theory wrong) and WRITE_SIZE 10.4->36 MB: L2 was MERGING the 8B-stride-2KB
// kv epilogue stores; NT bypassed the merge -> 4x write amplification,
// scan 53->63 us. What survives: gating reads miss L2 (17.5 MB FETCH vs
// 26 MB set). scan13 shrinks the set instead of restructuring compute:
// gate stores gf = sigmoid(p3)*sigmoid(g) (8 MB) instead of disc/gk/phiq
// (24 MB); scan reconstructs with gate's EXACT exprs — disc=(1-gf)*mask,
// gk=relu(p1)*k*gf, phiq=relu(p2)*q — from hot kb/qb (2 MB each) + scalars
// (lane's 8 D share one e). Sigmoids stay amortized in gate (scan12's trap);
// no barrier (scan11's trap). Working set 26 -> ~14 MB = 1.75 MB/XCD (L2
// fits). +~32 mul/lane-step vs ~1150 cyc stall. Bit-identical values.
//
// Scan ledger: scan5 58 / scan6 101 / scan7 67 / scan8 54 / scan9 73 /
// scan10 65 / scan11 71 / scan12 112 / scan8+NT 63.
//
// Carried:
//  - proj mfma_f32_16x16x32_f16 Markidis hi+lo split (3 MFMA/frag): ~22
//    mantissa bits, rel err ~1e-6 (bf16's 2^-8 failed in R2/R3). acc fp32.
//  - scan8 unit layout: 4 d-splits, 32-lane halves, DPP reduce, depth-1
//    rotation, li==16 writer. attn overwrites vb (scan never reads vb).
//  - out: single f16x3 MFMA GEMM, grid 128 (R28), cached stores.

#define T_N   64
#define B_N   16
#define DIM_N 512
#define H_N   8
#define DH_N  64

#define OUT_ELEMS   524288   // T*B*DIM
#define KV_ELEMS    2097152  // B*H*FD*Dh

typedef _Float16 f16;
typedef f16   f16x8 __attribute__((ext_vector_type(8)));
typedef float f32x4 __attribute__((ext_vector_type(4)));

__device__ __forceinline__ float sigmoidf_(float x) {
    return 1.0f / (1.0f + __expf(-x));
}

// ---------------------------------------------------------------------------
// DPP half-wave (32-lane) sum reduction, VALU-pipe only (no LDS). Half sums
// valid in lanes 16-31 (lo half) and 48-63 (hi half). PROVEN in scan8.
// ---------------------------------------------------------------------------
template <int CTRL, int RM>
__device__ __forceinline__ float dpp_add_(float x) {
    int mv = __builtin_amdgcn_update_dpp(__float_as_int(x), __float_as_int(x),
                                         CTRL, RM, 0xF, false);
    return x + __int_as_float(mv);
}
__device__ __forceinline__ float half_reduce_dpp(float x) {
    x = dpp_add_<0xB1, 0xF>(x);   // quad_perm [1,0,3,2]  (xor 1)
    x = dpp_add_<0x4E, 0xF>(x);   // quad_perm [2,3,0,1]  (xor 2)
    x = dpp_add_<0x141, 0xF>(x);  // row_half_mirror      (xor 4 equiv)
    x = dpp_add_<0x140, 0xF>(x);  // row_mirror           (xor 8 equiv)
    x = dpp_add_<0x142, 0xA>(x);  // row_bcast15 -> rows 1,3 (xor 16 equiv)
    return x;
}

// ---------------------------------------------------------------------------
// f16x3 split helper (PROVEN in proj): fp32 -> (hi, lo) f16 pair, ~22 bits.
// ---------------------------------------------------------------------------
__device__ __forceinline__ void cvt_split_store(f16* __restrict__ dh,
                                                f16* __restrict__ dl,
                                                float4 v0, float4 v1) {
    float x[8] = {v0.x, v0.y, v0.z, v0.w, v1.x, v1.y, v1.z, v1.w};
    f16x8 h, lo;
    #pragma unroll
    for (int e = 0; e < 8; ++e) {
        f16 hh = (f16)x[e];
        h[e]  = hh;
        lo[e] = (f16)(x[e] - (float)hh);
    }
    *(f16x8*)dh = h;
    *(f16x8*)dl = lo;
}

// ---------------------------------------------------------------------------
// mfma64_core: 64x64 tile f16x3 MFMA GEMM body (PROVEN, R19/R28).
// C[m][n] = sum_k A[m][k]*W[n][k] (+ bias[n]). Cached stores (NT reverted).
// ---------------------------------------------------------------------------
__device__ __forceinline__ void mfma64_core(const float* __restrict__ A,
                                            const float* __restrict__ W,
                                            const float* __restrict__ bias,
                                            float* __restrict__ C, int N,
                                            int mb, int nb) {
    const int nbase = nb * 64;
    if (nbase >= N) return;
    const int mbase = mb * 64;

    __shared__ f16 AsH[2][64][40];
    __shared__ f16 AsL[2][64][40];
    __shared__ f16 BsH[2][64][40];
    __shared__ f16 BsL[2][64][40];

    const int tid = threadIdx.x;
    const int sr = tid >> 2;
    const int kq = (tid & 3) << 3;
    const bool wok = (nbase + sr) < N;
    const float* Ap = A + (size_t)(mbase + sr) * 512 + kq;
    const float* Wp = W + (size_t)(nbase + sr) * 512 + kq;

    const int l  = tid & 63;
    const int w  = tid >> 6;
    const int wr = (w >> 1) << 5;
    const int wc = (w & 1) << 5;
    const int lr = l & 15;
    const int lk = (l >> 4) << 3;

    f32x4 acc[2][2] = {};

    float4 xa0 = *(const float4*)(Ap);
    float4 xa1 = *(const float4*)(Ap + 4);
    float4 wb0 = wok ? *(const float4*)(Wp)     : make_float4(0.f, 0.f, 0.f, 0.f);
    float4 wb1 = wok ? *(const float4*)(Wp + 4) : make_float4(0.f, 0.f, 0.f, 0.f);
    cvt_split_store(&AsH[0][sr][kq], &AsL[0][sr][kq], xa0, xa1);
    cvt_split_store(&BsH[0][sr][kq], &BsL[0][sr][kq], wb0, wb1);

    for (int k0 = 0; k0 < 512; k0 += 32) {
        const int buf = (k0 >> 5) & 1;
        __syncthreads();
        const bool more = (k0 + 32) < 512;
        if (more) {
            xa0 = *(const float4*)(Ap + k0 + 32);
            xa1 = *(const float4*)(Ap + k0 + 36);
            wb0 = wok ? *(const float4*)(Wp + k0 + 32) : make_float4(0.f, 0.f, 0.f, 0.f);
            wb1 = wok ? *(const float4*)(Wp + k0 + 36) : make_float4(0.f, 0.f, 0.f, 0.f);
        }

        f16x8 aH[2], aL[2], bH[2], bL[2];
        #pragma unroll
        for (int i = 0; i < 2; ++i) {
            const int row = wr + i * 16 + lr;
            aH[i] = *(const f16x8*)&AsH[buf][row][lk];
            aL[i] = *(const f16x8*)&AsL[buf][row][lk];
        }
        #pragma unroll
        for (int j = 0; j < 2; ++j) {
            const int col = wc + j * 16 + lr;
            bH[j] = *(const f16x8*)&BsH[buf][col][lk];
            bL[j] = *(const f16x8*)&BsL[buf][col][lk];
        }

        #pragma unroll
        for (int i = 0; i < 2; ++i)
            #pragma unroll
            for (int j = 0; j < 2; ++j) {
                acc[i][j] = __builtin_amdgcn_mfma_f32_16x16x32_f16(aH[i], bH[j], acc[i][j], 0, 0, 0);
                acc[i][j] = __builtin_amdgcn_mfma_f32_16x16x32_f16(aH[i], bL[j], acc[i][j], 0, 0, 0);
                acc[i][j] = __builtin_amdgcn_mfma_f32_16x16x32_f16(aL[i], bH[j], acc[i][j], 0, 0, 0);
            }

        if (more) {
            const int nbuf = buf ^ 1;
            cvt_split_store(&AsH[nbuf][sr][kq], &AsL[nbuf][sr][kq], xa0, xa1);
            cvt_split_store(&BsH[nbuf][sr][kq], &BsL[nbuf][sr][kq], wb0, wb1);
        }
    }

    // C/D layout (m89/m91): col = lane&15, row = (lane>>4)*4 + reg
    #pragma unroll
    for (int j = 0; j < 2; ++j) {
        const int n = nbase + wc + j * 16 + lr;
        if (n < N) {
            const float bv = bias ? bias[n] : 0.f;
            #pragma unroll
            for (int i = 0; i < 2; ++i) {
                #pragma unroll
                for (int q = 0; q < 4; ++q) {
                    const int m = mbase + wr + i * 16 + ((l >> 4) << 2) + q;
                    C[(size_t)m * N + n] = acc[i][j][q] + bv;
                }
            }
        }
    }
}

struct ProjW {
    const float* W[8];
    float*       D[8];
};

// proj (R19, PROVEN): grid 1024, id = z + 8*(m + 16*n); XCD = z.
__global__ __launch_bounds__(256) void proj_mfma_kernel(const float* __restrict__ X,
                                                        ProjW a) {
    const int id = blockIdx.x;
    const int z = id & 7;
    const int rem = id >> 3;
    const int mb = rem & 15;
    const int nb = rem >> 4;
    const int N = (z < 5) ? 512 : 32;
    mfma64_core(X, a.W[z], nullptr, a.D[z], N, mb, nb);
}

// out (R28): one f16x3 MFMA GEMM, grid 128 = 16 mb x 8 nb.
__global__ __launch_bounds__(256) void out_mfma_kernel(const float* __restrict__ A,
                                                       const float* __restrict__ W,
                                                       const float* __restrict__ bias,
                                                       float* __restrict__ C) {
    const int id = blockIdx.x;
    const int mb = id & 15;
    const int nb = id >> 4;
    mfma64_core(A, W, bias, C, 512, mb, nb);
}

// ---------------------------------------------------------------------------
// gate13 (R34): store ONLY gf = sigmoid(p3)*sigmoid(g) per (t,b,h,D) [8 MB]
// and gv = v*sigmoid(b) per (t,b,h,d) [2 MB]. disc/gk/phiq reconstructed in
// scan13 with identical fp32 expressions -> bit-identical. grid (8 h, 1024
// rows) -> wg id % 8 = h (writer XCD = scan reader XCD).
// ---------------------------------------------------------------------------
__global__ __launch_bounds__(256) void gate13_kernel(
    const float* __restrict__ vb,  const float* __restrict__ bb,
    const float* __restrict__ gb,  const float* __restrict__ p3b,
    float* __restrict__ gf_g, float* __restrict__ gv_g) {
    const int h = blockIdx.x;
    const int row = blockIdx.y;        // t*16 + b
    const int D = threadIdx.x;
    const int e = D >> 6, di = D & 63;
    const size_t base = (size_t)row * 512 + h * 64;
    const size_t pb = (size_t)row * 32 + h * 4;

    float g = gb[base + di];
    float p3 = p3b[pb + e];

    gf_g[((size_t)row * 8 + h) * 256 + D] = sigmoidf_(p3) * sigmoidf_(g);
    if (D < 64)
        gv_g[((size_t)row * 8 + h) * 64 + D] = vb[base + D] * sigmoidf_(bb[base + D]);
}

// ---------------------------------------------------------------------------
// scan13 (R34): scan8 structure; gating reconstructed from gf + hot kb/qb.
// Grid 512: blk = s*128 + bh (XCD = bh%8 = h). Block 256 thr = 4 waves;
// wave = 2 INDEPENDENT 32-lane halves. Half (l>>5) owns cols
// s*16+w*4+2*half+{0,1}. Lane li = l&31 owns D = 8*li..8*li+7 = one e
// (e=li>>3, di0=8*(li&7)). Per step loads: gf 2xfloat4 (8 MB region),
// k/q 2xfloat4 each (hot 2 MB proj buffers), p1/p2/term scalars, gv float2.
// disc=(1-gf)*mask, gk=relu(p1)*k*gf, phiq=relu(p2)*q — gate's exact exprs.
// Recurrence + DPP reduce = scan8 verbatim. attn overwrites vb (scan never
// reads vb; gv is precomputed). Depth-1 rotation.
// ---------------------------------------------------------------------------
__global__ __launch_bounds__(256) void scan13_kernel(
    const float* __restrict__ gf_g, const float* __restrict__ gv_g,
    const float* __restrict__ kb, const float* __restrict__ qb,
    const float* __restrict__ p1b, const float* __restrict__ p2b,
    const int* __restrict__ term,
    float* __restrict__ vb /* attn out */,
    const float* __restrict__ kv0, const float* __restrict__ nm0,
    float* __restrict__ dout) {
    const int blk = blockIdx.x;       // 512 = 4 splits x 128 bh
    const int bh = blk & 127;
    const int s  = blk >> 7;          // 0..3
    const int b  = bh >> 3;
    const int h  = bh & 7;
    const int tid = threadIdx.x;
    const int w = tid >> 6;
    const int l = tid & 63;
    const int half = l >> 5;
    const int li = l & 31;
    const int d0 = s * 16 + w * 4 + half * 2;   // lane's 2 d-cols
    const int D0 = li << 3;                     // lane's 8 D
    const int di0 = D0 & 63;                    // 8*(li&7)
    const int e   = D0 >> 6;                    // li>>3

    float kv[8][2];
    float nm[8];
    {
        const float* kp = kv0 + ((size_t)bh * 256 + D0) * 64 + d0;
        #pragma unroll
        for (int j = 0; j < 8; ++j) {
            float2 r = *(const float2*)(kp + (size_t)j * 64);
            kv[j][0] = r.x; kv[j][1] = r.y;
        }
        float4 na  = *(const float4*)(nm0 + (size_t)bh * 256 + D0);
        float4 nb_ = *(const float4*)(nm0 + (size_t)bh * 256 + D0 + 4);
        nm[0] = na.x; nm[1] = na.y; nm[2] = na.z; nm[3] = na.w;
        nm[4] = nb_.x; nm[5] = nb_.y; nm[6] = nb_.z; nm[7] = nb_.w;
    }

    // current-step register buffers
    float4 cf0, cf1, ck0, ck1, cq0, cq1;
    float  cp1, cp2, cmask;
    float2 cgv;
    {
        const size_t go = ((size_t)b * 8 + h) * 256 + D0;
        const size_t base = (size_t)b * 512 + h * 64;
        const size_t pb = (size_t)b * 32 + h * 4 + e;
        cf0 = *(const float4*)(gf_g + go); cf1 = *(const float4*)(gf_g + go + 4);
        ck0 = *(const float4*)(kb + base + di0); ck1 = *(const float4*)(kb + base + di0 + 4);
        cq0 = *(const float4*)(qb + base + di0); cq1 = *(const float4*)(qb + base + di0 + 4);
        cp1 = p1b[pb]; cp2 = p2b[pb];
        cmask = 1.0f - (float)term[b];
        cgv = *(const float2*)(gv_g + ((size_t)b * 8 + h) * 64 + d0);
    }

    for (int t = 0; t < T_N; ++t) {
        const int row = t * B_N + b;
        const size_t base = (size_t)row * 512 + h * 64;

        // prefetch t+1 (depth-1, scan8-proven)
        float4 nf0 = {}, nf1 = {}, nk0 = {}, nk1 = {}, nq0 = {}, nq1 = {};
        float  np1 = 0.f, np2 = 0.f, nmask = 0.f;
        float2 ngv = {};
        if (t + 1 < T_N) {
            const size_t go2 = ((size_t)(row + B_N) * 8 + h) * 256 + D0;
            const size_t nb2 = (size_t)(row + B_N) * 512 + h * 64;
            const size_t npb = (size_t)(row + B_N) * 32 + h * 4 + e;
            nf0 = *(const float4*)(gf_g + go2); nf1 = *(const float4*)(gf_g + go2 + 4);
            nk0 = *(const float4*)(kb + nb2 + di0); nk1 = *(const float4*)(kb + nb2 + di0 + 4);
            nq0 = *(const float4*)(qb + nb2 + di0); nq1 = *(const float4*)(qb + nb2 + di0 + 4);
            np1 = p1b[npb]; np2 = p2b[npb];
            nmask = 1.0f - (float)term[row + B_N];
            ngv = *(const float2*)(gv_g + ((size_t)(row + B_N) * 8 + h) * 64 + d0);
        }

        // reconstruct gating (gate13's exact fp32 exprs -> bit-identical)
        const float gfj[8] = {cf0.x, cf0.y, cf0.z, cf0.w, cf1.x, cf1.y, cf1.z, cf1.w};
        const float kj[8]  = {ck0.x, ck0.y, ck0.z, ck0.w, ck1.x, ck1.y, ck1.z, ck1.w};
        const float qj[8]  = {cq0.x, cq0.y, cq0.z, cq0.w, cq1.x, cq1.y, cq1.z, cq1.w};
        const float r1 = fmaxf(cp1, 0.f);
        const float r2 = fmaxf(cp2, 0.f);

        float den = 0.f, n0 = 0.f, n1 = 0.f;
        #pragma unroll
        for (int j = 0; j < 8; ++j) {
            const float dj  = (1.0f - gfj[j]) * cmask;
            const float gkj = r1 * kj[j] * gfj[j];
            const float phj = r2 * qj[j];
            nm[j] = dj * nm[j] + gkj;
            den = fmaf(phj, nm[j], den);
            kv[j][0] = dj * kv[j][0] + gkj * cgv.x; n0 = fmaf(phj, kv[j][0], n0);
            kv[j][1] = dj * kv[j][1] + gkj * cgv.y; n1 = fmaf(phj, kv[j][1], n1);
        }

        n0  = half_reduce_dpp(n0);
        n1  = half_reduce_dpp(n1);
        den = half_reduce_dpp(den);

        if (li == 16) {
            vb[base + d0]     = n0 / (den + 1e-6f);
            vb[base + d0 + 1] = n1 / (den + 1e-6f);
        }

        cf0 = nf0; cf1 = nf1; ck0 = nk0; ck1 = nk1; cq0 = nq0; cq1 = nq1;
        cp1 = np1; cp2 = np2; cmask = nmask; cgv = ngv;
    }

    {
        float* kp = dout + OUT_ELEMS + ((size_t)bh * 256 + D0) * 64 + d0;
        #pragma unroll
        for (int j = 0; j < 8; ++j)
            *(float2*)(kp + (size_t)j * 64) = make_float2(kv[j][0], kv[j][1]);
        if (s == 0 && w == 0 && half == 0) {
            float* np = dout + OUT_ELEMS + KV_ELEMS + (size_t)bh * 256 + D0;
            *(float4*)np       = make_float4(nm[0], nm[1], nm[2], nm[3]);
            *(float4*)(np + 4) = make_float4(nm[4], nm[5], nm[6], nm[7]);
        }
    }
}

// ---------------------------------------------------------------------------
extern "C" void kernel_launch(void* const* d_in, const int* in_sizes, int n_in,
                              void* d_out, int out_size, void* d_ws, size_t ws_size,
                              hipStream_t stream) {
    (void)in_sizes; (void)n_in; (void)out_size; (void)ws_size;

    const float* X    = (const float*)d_in[0];
    const int*   term = (const int*)  d_in[1];
    const float* kv0  = (const float*)d_in[2];
    const float* nm0  = (const float*)d_in[3];
    const float* Wo   = (const float*)d_in[12];
    const float* bo   = (const float*)d_in[13];

    float* out = (float*)d_out;

    // ---- workspace (proj 10.4 MB + gf 8 MB + gv 2 MB ~ 20.5 MB) ----
    float* qb  = (float*)d_ws;            // proj outputs
    float* kb  = qb  + 524288;
    float* vb  = kb  + 524288;            // v, later attn
    float* bb  = vb  + 524288;
    float* gb  = bb  + 524288;
    float* p1b = gb  + 524288;
    float* p2b = p1b + 32768;
    float* p3b = p2b + 32768;
    float* gf_g = p3b + 32768;            // 8 MB gf region (ex-disc_g)
    float* gv_g = gf_g + 2097152;         // 2 MB gv

    ProjW pa;
    pa.W[0] = (const float*)d_in[4];  pa.W[1] = (const float*)d_in[5];
    pa.W[2] = (const float*)d_in[6];  pa.W[3] = (const float*)d_in[7];
    pa.W[4] = (const float*)d_in[8];  pa.W[5] = (const float*)d_in[9];
    pa.W[6] = (const float*)d_in[10]; pa.W[7] = (const float*)d_in[11];
    pa.D[0] = qb;  pa.D[1] = kb;  pa.D[2] = vb;  pa.D[3] = bb;
    pa.D[4] = gb;  pa.D[5] = p1b; pa.D[6] = p2b; pa.D[7] = p3b;
    proj_mfma_kernel<<<1024, 256, 0, stream>>>(X, pa);

    gate13_kernel<<<dim3(8, 1024), 256, 0, stream>>>(vb, bb, gb, p3b,
                                                     gf_g, gv_g);
    scan13_kernel<<<512, 256, 0, stream>>>(gf_g, gv_g, kb, qb, p1b, p2b, term,
                                           vb, kv0, nm0, out);
    // out = attn @ Wo^T + bo — single f16x3 MFMA GEMM (R28)
    out_mfma_kernel<<<128, 256, 0, stream>>>(vb, Wo, bo, out);
}